// Round 3
// baseline (1813.820 us; speedup 1.0000x reference)
//
#include <hip/hip_runtime.h>
#include <hip/hip_fp16.h>
#include <cstdint>
#include <cstddef>

// Problem constants (fixed by the reference)
#define EPSV 1e-5f
constexpr int Bb = 128, Tt = 2048, Ff = 80, NCc = 10, Hh = 32;
constexpr int Nn = Bb * Tt;  // 262144 rows

// ---------------- workspace layout (units: floats) ----------------
// Overlaid big regions (live ranges; all pairwise-disjoint in TIME or SPACE):
//   h1  f16  [0,     128N)  live P1 -> P2
//   h2  f16  [128N,  192N)  live P2 -> P3
//   h3  f32  [0,      64N)  live P3 -> P4   (h1 dead)
//   xp  f16  [64N,   160N)  live P4 -> GRU  (h1/h2 dead; disjoint from h3)
//   gru f32  [0,      64N)  live GRU -> pool (h3 dead)
//   scores   [64N,    65N)  live attn -> pool (xp dead)
// Tail (stats partials, scales, bmax/bsum/pooled) at 192N — above everything,
// since stats/scales are concurrently live with the big regions.
// Total extent = 192N + 66688 floats ~= 201.6 MB.
constexpr size_t OFF_H1 = 0;
constexpr size_t OFF_H3 = 0;
constexpr size_t OFF_GRU = 0;
constexpr size_t OFF_XP = (size_t)Nn * 64;
constexpr size_t OFF_SCORES = (size_t)Nn * 64;  // after GRU, xp is dead
constexpr size_t OFF_H2 = (size_t)Nn * 128;
constexpr size_t TAIL = (size_t)Nn * 192;
constexpr size_t P1o = TAIL;                 // 64*256*2 = 32768
constexpr size_t P2o = P1o + 64 * 256 * 2;   // 64*128*2 = 16384
constexpr size_t P3o = P2o + 64 * 128 * 2;   // 64*64*2  = 8192
constexpr size_t PZEND = P3o + 64 * 64 * 2;  // end of zeroed region
constexpr size_t SC1o = PZEND;               // 256+256
constexpr size_t SC2o = SC1o + 512;          // 128+128
constexpr size_t SC3o = SC2o + 256;          // 64+64
constexpr size_t BMAXo = SC3o + 128;         // 128
constexpr size_t BSUMo = BMAXo + 128;        // 128
constexpr size_t POOLEDo = BSUMo + 128;      // 128*64
constexpr size_t WS_EXTENT = POOLEDo + 128 * 64;  // floats

struct alignas(8) half4 { __half x, y, z, w; };

__global__ __launch_bounds__(256) void zero_kernel(float* __restrict__ p, int n) {
  const int i = blockIdx.x * 256 + threadIdx.x;
  if (i < n) p[i] = 0.f;
}

// ---------------------------------------------------------------------------
// Generic FC kernel: C[r, coloff+col] = act(A[r,:]) @ W.T + bias
//   - A [Nrows][K] row-major (fp32 or f16 per A16); W [COUT][K] fp32
//   - optional BN+ReLU applied to A on load (scale/shift per k)
//   - optional column stats (sum,sumsq) of fp32 OUTPUT into bucketed partials
//   - C stored fp32 or f16 per C16 (stats always from fp32 values)
// Tile 64x64, K-tiles of 32, block 256, 4x4 micro-tile.
// ---------------------------------------------------------------------------
template <int K, bool BN_IN, bool STATS, bool A16, bool C16>
__global__ __launch_bounds__(256) void fc_kernel(
    const void* __restrict__ Av, const float* __restrict__ W,
    const float* __restrict__ bias, const float* __restrict__ scl,
    const float* __restrict__ shf, void* __restrict__ Cv, int ldc, int coloff,
    int COUT, float* __restrict__ Pstat) {
  __shared__ float smem[32 * 68 * 2 + 512];
  float* As = smem;
  float* Bs = smem + 32 * 68;
  float* Ss = smem + 32 * 68 * 2;
  float* Sh = Ss + 256;

  const int tid = threadIdx.x;
  const int r0 = blockIdx.x * 64;
  const int nb0 = blockIdx.y * 64;
  const int m0 = (tid >> 4) * 4;
  const int n0 = (tid & 15) * 4;

  if (BN_IN) {
    for (int k = tid; k < K; k += 256) {
      Ss[k] = scl[k];
      Sh[k] = shf[k];
    }
  }

  float acc[4][4] = {};

  constexpr int NKT = (K + 31) / 32;
  for (int kt = 0; kt < NKT; ++kt) {
    const int k0 = kt * 32;
    __syncthreads();
#pragma unroll
    for (int rep = 0; rep < 2; ++rep) {
      const int li = rep * 256 + tid;
      const int row = li >> 3;      // 0..63
      const int ko = (li & 7) * 4;  // 0..28
      float av[4] = {0.f, 0.f, 0.f, 0.f};
      if (k0 + ko < K) {
        if (A16) {
          const half4 v = *(const half4*)&(
              (const __half*)Av)[(size_t)(r0 + row) * K + k0 + ko];
          av[0] = __half2float(v.x); av[1] = __half2float(v.y);
          av[2] = __half2float(v.z); av[3] = __half2float(v.w);
        } else {
          const float4 v =
              *(const float4*)&((const float*)Av)[(size_t)(r0 + row) * K + k0 + ko];
          av[0] = v.x; av[1] = v.y; av[2] = v.z; av[3] = v.w;
        }
        if (BN_IN) {
#pragma unroll
          for (int e = 0; e < 4; ++e)
            av[e] = fmaxf(av[e] * Ss[k0 + ko + e] + Sh[k0 + ko + e], 0.f);
        }
      }
#pragma unroll
      for (int e = 0; e < 4; ++e) As[(ko + e) * 68 + row] = av[e];
      float bv[4] = {0.f, 0.f, 0.f, 0.f};
      const int wn = nb0 + row;
      if (wn < COUT && k0 + ko < K) {
        const float4 v = *(const float4*)&W[(size_t)wn * K + k0 + ko];
        bv[0] = v.x; bv[1] = v.y; bv[2] = v.z; bv[3] = v.w;
      }
#pragma unroll
      for (int e = 0; e < 4; ++e) Bs[(ko + e) * 68 + row] = bv[e];
    }
    __syncthreads();
#pragma unroll
    for (int kk = 0; kk < 32; ++kk) {
      const float4 a4 = *(const float4*)&As[kk * 68 + m0];
      const float4 b4 = *(const float4*)&Bs[kk * 68 + n0];
      const float a[4] = {a4.x, a4.y, a4.z, a4.w};
      const float b[4] = {b4.x, b4.y, b4.z, b4.w};
#pragma unroll
      for (int i = 0; i < 4; ++i)
#pragma unroll
        for (int j = 0; j < 4; ++j) acc[i][j] = fmaf(a[i], b[j], acc[i][j]);
    }
  }

  // epilogue: bias, store (fp32 or f16), stats from fp32 values
  float colsum[4] = {0.f, 0.f, 0.f, 0.f};
  float colsq[4] = {0.f, 0.f, 0.f, 0.f};
#pragma unroll
  for (int i = 0; i < 4; ++i) {
    const int r = r0 + m0 + i;
    float vv[4];
#pragma unroll
    for (int j = 0; j < 4; ++j) {
      const int col = nb0 + n0 + j;
      float v = 0.f;
      if (col < COUT) v = acc[i][j] + bias[col];
      vv[j] = v;
      if (STATS) {
        colsum[j] += v;
        colsq[j] += v * v;
      }
    }
    if (nb0 + n0 + 3 < COUT) {
      if (C16) {
        half4 o;
        o.x = __float2half(vv[0]); o.y = __float2half(vv[1]);
        o.z = __float2half(vv[2]); o.w = __float2half(vv[3]);
        *(half4*)&((__half*)Cv)[(size_t)r * ldc + coloff + nb0 + n0] = o;
      } else {
        float4 o;
        o.x = vv[0]; o.y = vv[1]; o.z = vv[2]; o.w = vv[3];
        *(float4*)&((float*)Cv)[(size_t)r * ldc + coloff + nb0 + n0] = o;
      }
    } else {
#pragma unroll
      for (int j = 0; j < 4; ++j) {
        const int col = nb0 + n0 + j;
        if (col < COUT) {
          if (C16)
            ((__half*)Cv)[(size_t)r * ldc + coloff + col] = __float2half(vv[j]);
          else
            ((float*)Cv)[(size_t)r * ldc + coloff + col] = vv[j];
        }
      }
    }
  }
  if (STATS) {
    __syncthreads();
    const int rg = tid >> 4;
#pragma unroll
    for (int j = 0; j < 4; ++j) {
      smem[(n0 + j) * 16 + rg] = colsum[j];
      smem[1024 + (n0 + j) * 16 + rg] = colsq[j];
    }
    __syncthreads();
    if (tid < 64) {
      float s = 0.f, q = 0.f;
#pragma unroll
      for (int g = 0; g < 16; ++g) {
        s += smem[tid * 16 + g];
        q += smem[1024 + tid * 16 + g];
      }
      const int col = nb0 + tid;
      if (col < COUT) {
        const int bkt = blockIdx.x & 63;
        atomicAdd(&Pstat[(size_t)bkt * COUT + col], s);
        atomicAdd(&Pstat[(size_t)64 * COUT + (size_t)bkt * COUT + col], q);
      }
    }
  }
}

__global__ __launch_bounds__(256) void bn_finalize(
    const float* __restrict__ P, int COUT, int nrows,
    const float* __restrict__ g, const float* __restrict__ be,
    float* __restrict__ scl, float* __restrict__ shf) {
  const int c = threadIdx.x;
  if (c < COUT) {
    float s = 0.f, q = 0.f;
    for (int b = 0; b < 64; ++b) {
      s += P[(size_t)b * COUT + c];
      q += P[(size_t)64 * COUT + (size_t)b * COUT + c];
    }
    const float invN = 1.f / (float)nrows;
    const float m = s * invN;
    const float var = q * invN - m * m;
    const float inv = rsqrtf(var + EPSV);
    scl[c] = g[c] * inv;
    shf[c] = be[c] - m * g[c] * inv;
  }
}

// ---------------------------------------------------------------------------
// biGRU: one wave per (batch, direction). xp is f16 [N][192] (+bih folded).
// h in lanes 0..31, broadcast via readlane; Whh rows resident in VGPRs.
// Prefetch ring keeps RAW halfs; convert at use to preserve latency hiding.
// ---------------------------------------------------------------------------
__device__ __forceinline__ float readlane_f(float v, int l) {
  return __uint_as_float(
      (unsigned)__builtin_amdgcn_readlane((int)__float_as_uint(v), l));
}
__device__ __forceinline__ float sigmoid_f(float x) {
  return 1.f / (1.f + __expf(-x));
}
__device__ __forceinline__ float tanh_f(float x) {
  return 1.f - 2.f / (__expf(2.f * x) + 1.f);
}

__global__ __launch_bounds__(64) void gru_kernel(
    const __half* __restrict__ xp, const float* __restrict__ Whh_f,
    const float* __restrict__ bhh_f, const float* __restrict__ Whh_b,
    const float* __restrict__ bhh_b, float* __restrict__ out) {
  const int blk = blockIdx.x;
  const int b = blk >> 1, dir = blk & 1;
  const int lane = threadIdx.x;
  const float* __restrict__ Whh = dir ? Whh_b : Whh_f;
  const float* __restrict__ bhh = dir ? bhh_b : bhh_f;

  float w0[32], w1[32];
#pragma unroll
  for (int j4 = 0; j4 < 8; ++j4) {
    const float4 v = *(const float4*)&Whh[(size_t)lane * 32 + j4 * 4];
    w0[j4 * 4 + 0] = v.x; w0[j4 * 4 + 1] = v.y;
    w0[j4 * 4 + 2] = v.z; w0[j4 * 4 + 3] = v.w;
    float4 u = make_float4(0.f, 0.f, 0.f, 0.f);
    if (lane < 32) u = *(const float4*)&Whh[(size_t)(64 + lane) * 32 + j4 * 4];
    w1[j4 * 4 + 0] = u.x; w1[j4 * 4 + 1] = u.y;
    w1[j4 * 4 + 2] = u.z; w1[j4 * 4 + 3] = u.w;
  }
  const float bh0 = bhh[lane];
  const float bh1 = (lane < 32) ? bhh[64 + lane] : 0.f;

  float h = 0.f;
  const size_t base_b = (size_t)b * Tt;

  __half xa[8], xb[8];  // raw halfs; convert at use
#pragma unroll
  for (int u = 0; u < 8; ++u) {
    const int t = dir ? (Tt - 1 - u) : u;
    const __half* p = &xp[(base_b + t) * 192 + dir * 96];
    xa[u] = p[lane];
    xb[u] = (lane < 32) ? p[64 + lane] : __half(0.f);
  }

  for (int s = 0; s < Tt; s += 8) {
#pragma unroll
    for (int u = 0; u < 8; ++u) {
      const int st = s + u;
      const int t = dir ? (Tt - 1 - st) : st;
      const float xg0 = __half2float(xa[u]);
      const float xg1 = __half2float(xb[u]);
      const int sp = st + 8;
      if (sp < Tt) {
        const int tp = dir ? (Tt - 1 - sp) : sp;
        const __half* p = &xp[(base_b + tp) * 192 + dir * 96];
        xa[u] = p[lane];
        xb[u] = (lane < 32) ? p[64 + lane] : __half(0.f);
      }
      float a0 = 0.f, a0b = 0.f, a1 = 0.f, a1b = 0.f;
#pragma unroll
      for (int j = 0; j < 32; j += 2) {
        const float hj = readlane_f(h, j);
        const float hj1 = readlane_f(h, j + 1);
        a0 = fmaf(hj, w0[j], a0);
        a0b = fmaf(hj1, w0[j + 1], a0b);
        a1 = fmaf(hj, w1[j], a1);
        a1b = fmaf(hj1, w1[j + 1], a1b);
      }
      const float gh0 = bh0 + a0 + a0b;  // rows 0..63 (r | z)
      const float gh1 = bh1 + a1 + a1b;  // rows 64..95 (n), lanes<32
      const float s0 = xg0 + gh0;
      const float s0z = __shfl(s0, (lane & 31) + 32);
      const float r = sigmoid_f(s0);
      const float z = sigmoid_f(s0z);
      const float n = tanh_f(xg1 + r * gh1);
      const float hn = (1.f - z) * n + z * h;
      h = hn;
      if (lane < 32) out[(base_b + t) * 64 + dir * 32 + lane] = hn;
    }
  }
}

// ---------------------------------------------------------------------------
__global__ __launch_bounds__(256) void attn_score_kernel(
    const float* __restrict__ G, const float* __restrict__ Wa1,
    const float* __restrict__ ba1, const float* __restrict__ Wa2,
    const float* __restrict__ ba2, float* __restrict__ scores) {
  const int n = blockIdx.x * 256 + threadIdx.x;
  const float* g = &G[(size_t)n * 64];
  float gv[64];
#pragma unroll
  for (int j4 = 0; j4 < 16; ++j4) {
    const float4 v = *(const float4*)&g[j4 * 4];
    gv[j4 * 4 + 0] = v.x; gv[j4 * 4 + 1] = v.y;
    gv[j4 * 4 + 2] = v.z; gv[j4 * 4 + 3] = v.w;
  }
  float sc = ba2[0];
#pragma unroll 4
  for (int l = 0; l < 32; ++l) {
    float a = ba1[l];
#pragma unroll
    for (int j = 0; j < 64; ++j) a = fmaf(Wa1[l * 64 + j], gv[j], a);
    sc = fmaf(Wa2[l], tanh_f(a), sc);
  }
  scores[n] = sc;
}

__global__ __launch_bounds__(256) void softmax_stats_kernel(
    const float* __restrict__ scores, float* __restrict__ bmax,
    float* __restrict__ bsum) {
  const int b = blockIdx.x;
  const int tid = threadIdx.x;
  __shared__ float red[256];
  const float* s = &scores[(size_t)b * Tt];
  float m = -1e30f;
  for (int t = tid; t < Tt; t += 256) m = fmaxf(m, s[t]);
  red[tid] = m;
  __syncthreads();
  for (int off = 128; off > 0; off >>= 1) {
    if (tid < off) red[tid] = fmaxf(red[tid], red[tid + off]);
    __syncthreads();
  }
  m = red[0];
  __syncthreads();
  float e = 0.f;
  for (int t = tid; t < Tt; t += 256) e += __expf(s[t] - m);
  red[tid] = e;
  __syncthreads();
  for (int off = 128; off > 0; off >>= 1) {
    if (tid < off) red[tid] += red[tid + off];
    __syncthreads();
  }
  if (tid == 0) {
    bmax[b] = m;
    bsum[b] = red[0];
  }
}

__global__ __launch_bounds__(256) void pooled_kernel(
    const float* __restrict__ G, const float* __restrict__ scores,
    const float* __restrict__ bmax, const float* __restrict__ bsum,
    float* __restrict__ pooled) {
  const int b = blockIdx.x;
  const int d = threadIdx.x & 63;
  const int q = threadIdx.x >> 6;
  const float m = bmax[b];
  float acc = 0.f;
  for (int t = q; t < Tt; t += 4) {
    const float w = __expf(scores[(size_t)b * Tt + t] - m);
    acc += w * G[((size_t)b * Tt + t) * 64 + d];
  }
  __shared__ float red[4][64];
  red[q][d] = acc;
  __syncthreads();
  if (threadIdx.x < 64) {
    const float v = red[0][d] + red[1][d] + red[2][d] + red[3][d];
    pooled[(size_t)b * 64 + d] = v / bsum[b];
  }
}

__global__ __launch_bounds__(128) void classifier_kernel(
    const float* __restrict__ pooled, const float* __restrict__ Wc1,
    const float* __restrict__ bc1, const float* __restrict__ gc,
    const float* __restrict__ bec, const float* __restrict__ Wc2,
    const float* __restrict__ bc2, float* __restrict__ out) {
  __shared__ float c1s[128][33];
  __shared__ float sA[32], sB[32];
  const int b = threadIdx.x;
  float pv[64];
#pragma unroll
  for (int j4 = 0; j4 < 16; ++j4) {
    const float4 v = *(const float4*)&pooled[(size_t)b * 64 + j4 * 4];
    pv[j4 * 4 + 0] = v.x; pv[j4 * 4 + 1] = v.y;
    pv[j4 * 4 + 2] = v.z; pv[j4 * 4 + 3] = v.w;
  }
#pragma unroll 2
  for (int j = 0; j < 32; ++j) {
    float a = bc1[j];
#pragma unroll
    for (int k = 0; k < 64; ++k) a = fmaf(Wc1[j * 64 + k], pv[k], a);
    c1s[b][j] = a;
  }
  __syncthreads();
  if (b < 32) {
    float s = 0.f, q = 0.f;
    for (int r = 0; r < 128; ++r) {
      const float v = c1s[r][b];
      s += v;
      q += v * v;
    }
    const float m = s * (1.f / 128.f);
    const float var = q * (1.f / 128.f) - m * m;
    const float inv = rsqrtf(var + EPSV);
    sA[b] = gc[b] * inv;
    sB[b] = bec[b] - m * gc[b] * inv;
  }
  __syncthreads();
  float act[32];
#pragma unroll
  for (int j = 0; j < 32; ++j)
    act[j] = fmaxf(c1s[b][j] * sA[j] + sB[j], 0.f);
#pragma unroll
  for (int k = 0; k < NCc; ++k) {
    float o = bc2[k];
#pragma unroll
    for (int j = 0; j < 32; ++j) o = fmaf(Wc2[k * 32 + j], act[j], o);
    out[(size_t)b * NCc + k] = o;
  }
}

// ---------------------------------------------------------------------------
extern "C" void kernel_launch(void* const* d_in, const int* in_sizes, int n_in,
                              void* d_out, int out_size, void* d_ws,
                              size_t ws_size, hipStream_t stream) {
  // Diagnostic guard: if the workspace is smaller than our layout, emit a
  // clean wrong-answer (zeros) instead of faulting — distinguishes
  // "ws too small" from genuine kernel bugs in the bench report.
  if (ws_size < WS_EXTENT * sizeof(float)) {
    zero_kernel<<<(out_size + 255) / 256, 256, 0, stream>>>((float*)d_out,
                                                            out_size);
    return;
  }

  const float* x = (const float*)d_in[0];
  const float* W1 = (const float*)d_in[1];
  const float* b1 = (const float*)d_in[2];
  const float* g1 = (const float*)d_in[3];
  const float* be1 = (const float*)d_in[4];
  const float* W2 = (const float*)d_in[5];
  const float* b2 = (const float*)d_in[6];
  const float* g2 = (const float*)d_in[7];
  const float* be2 = (const float*)d_in[8];
  const float* W3 = (const float*)d_in[9];
  const float* b3 = (const float*)d_in[10];
  const float* g3 = (const float*)d_in[11];
  const float* be3 = (const float*)d_in[12];
  const float* Wih_f = (const float*)d_in[13];
  const float* Whh_f = (const float*)d_in[14];
  const float* bih_f = (const float*)d_in[15];
  const float* bhh_f = (const float*)d_in[16];
  const float* Wih_b = (const float*)d_in[17];
  const float* Whh_b = (const float*)d_in[18];
  const float* bih_b = (const float*)d_in[19];
  const float* bhh_b = (const float*)d_in[20];
  const float* Wa1 = (const float*)d_in[21];
  const float* ba1 = (const float*)d_in[22];
  const float* Wa2 = (const float*)d_in[23];
  const float* ba2 = (const float*)d_in[24];
  const float* Wc1 = (const float*)d_in[25];
  const float* bc1 = (const float*)d_in[26];
  const float* gc = (const float*)d_in[27];
  const float* bec = (const float*)d_in[28];
  const float* Wc2 = (const float*)d_in[29];
  const float* bc2 = (const float*)d_in[30];

  float* ws = (float*)d_ws;
  __half* h1 = (__half*)(ws + OFF_H1);
  __half* h2 = (__half*)(ws + OFF_H2);
  float* h3 = ws + OFF_H3;
  __half* xp = (__half*)(ws + OFF_XP);
  float* gru = ws + OFF_GRU;

  // zero the stat-partial regions (ws poisoned 0xAA before every launch)
  {
    const int nz = (int)(PZEND - P1o);  // 57344 floats
    zero_kernel<<<(nz + 255) / 256, 256, 0, stream>>>(ws + P1o, nz);
  }

  const int rowblocks = Nn / 64;  // 4096

  // P1: x[N,80] @ W1.T -> h1 f16 [N,256] (+stats1)
  fc_kernel<80, false, true, false, true><<<dim3(rowblocks, 4), 256, 0, stream>>>(
      x, W1, b1, nullptr, nullptr, h1, 256, 0, 256, ws + P1o);
  bn_finalize<<<1, 256, 0, stream>>>(ws + P1o, 256, Nn, g1, be1, ws + SC1o,
                                     ws + SC1o + 256);
  // P2: relu(bn(h1)) @ W2.T -> h2 f16 [N,128] (+stats2)
  fc_kernel<256, true, true, true, true><<<dim3(rowblocks, 2), 256, 0, stream>>>(
      h1, W2, b2, ws + SC1o, ws + SC1o + 256, h2, 128, 0, 128, ws + P2o);
  bn_finalize<<<1, 128, 0, stream>>>(ws + P2o, 128, Nn, g2, be2, ws + SC2o,
                                     ws + SC2o + 128);
  // P3: relu(bn(h2)) @ W3.T -> h3 fp32 [N,64] (+stats3)
  fc_kernel<128, true, true, true, false><<<dim3(rowblocks, 1), 256, 0, stream>>>(
      h2, W3, b3, ws + SC2o, ws + SC2o + 128, h3, 64, 0, 64, ws + P3o);
  bn_finalize<<<1, 64, 0, stream>>>(ws + P3o, 64, Nn, g3, be3, ws + SC3o,
                                    ws + SC3o + 64);
  // P4: xp f16 [N,192] = relu(bn(h3)) @ [Wih_f; Wih_b].T + bih
  fc_kernel<64, true, false, false, true><<<dim3(rowblocks, 2), 256, 0, stream>>>(
      h3, Wih_f, bih_f, ws + SC3o, ws + SC3o + 64, xp, 192, 0, 96, nullptr);
  fc_kernel<64, true, false, false, true><<<dim3(rowblocks, 2), 256, 0, stream>>>(
      h3, Wih_b, bih_b, ws + SC3o, ws + SC3o + 64, xp, 192, 96, 96, nullptr);
  // biGRU scan
  gru_kernel<<<256, 64, 0, stream>>>(xp, Whh_f, bhh_f, Whh_b, bhh_b, gru);
  // attention
  attn_score_kernel<<<Nn / 256, 256, 0, stream>>>(gru, Wa1, ba1, Wa2, ba2,
                                                  ws + OFF_SCORES);
  softmax_stats_kernel<<<Bb, 256, 0, stream>>>(ws + OFF_SCORES, ws + BMAXo,
                                               ws + BSUMo);
  pooled_kernel<<<Bb, 256, 0, stream>>>(gru, ws + OFF_SCORES, ws + BMAXo,
                                        ws + BSUMo, ws + POOLEDo);
  // classifier
  classifier_kernel<<<1, 128, 0, stream>>>(ws + POOLEDo, Wc1, bc1, gc, bec,
                                           Wc2, bc2, (float*)d_out);
}